// Round 2
// baseline (29850.153 us; speedup 1.0000x reference)
//
#include <hip/hip_runtime.h>
#include <hip/hip_bf16.h>

// BiLSTM-CRF tagger, MI355X. Round 2: deadlock-proof + ws-guarded pipeline.
//   K2 fused embed-gather + xg GEMM (fp32 compute, bf16 store)
//   K3 cooperative LSTM recurrence: 256 blocks (128/dir), Whh in REGISTERS,
//      h exchange via agent-scope write-through atomics + flags + acquire fence,
//      bounded spin (clean bail instead of hang).
//   K4 head + log_softmax -> K5 Viterbi.

#define SEQ  2048
#define DINW 496
#define HDIM 768
#define G4   3072
#define CDIM 13
#define NWG  128          // workgroups per direction (2*NWG = 256 blocks total)
#define JPW  6            // h elements per workgroup (768/128)
#define SPIN_LIMIT (1u << 23)

__device__ __forceinline__ float sigf(float x) { return 1.0f / (1.0f + __expf(-x)); }
__device__ __forceinline__ float tanhf_fast(float x) {
    float ax = fabsf(x);
    float e  = __expf(-2.0f * ax);
    float t  = (1.0f - e) / (1.0f + e);
    return copysignf(t, x);
}

// ---------------- K2: xg = [we[x],ce[casing],pe[pos]] @ Wih^T + b  (bf16 out)
// C[2048][3072] = A[2048][496] * B[3072][496]^T, 64x64 tiles, BK=16 (496=31*16)
__global__ __launch_bounds__(256) void k_gemm_xg(
    const int* __restrict__ x, const int* __restrict__ casing, const int* __restrict__ pos,
    const float* __restrict__ we, const float* __restrict__ ce, const float* __restrict__ pe,
    const float* __restrict__ Wih_f, const float* __restrict__ b_f,
    const float* __restrict__ Wih_b, const float* __restrict__ b_b,
    __hip_bfloat16* __restrict__ xg_f, __hip_bfloat16* __restrict__ xg_b)
{
    __shared__ float As[16][68];
    __shared__ float Bs[16][68];
    int dir = blockIdx.z;
    const float* B    = dir ? Wih_b : Wih_f;
    const float* bias = dir ? b_b   : b_f;
    __hip_bfloat16* C = dir ? xg_b  : xg_f;
    int n0 = blockIdx.x * 64, m0 = blockIdx.y * 64;
    int tid = threadIdx.x;
    int tx = tid & 15, ty = tid >> 4;
    int lr = tid >> 2, lk = (tid & 3) * 4;

    int m = m0 + lr;
    const float* arow_w = we + (size_t)x[m] * 400;
    const float* arow_c = ce + (size_t)casing[m] * 32;
    const float* arow_p = pe + (size_t)pos[m] * 64;

    float acc[4][4] = {};
    for (int k0 = 0; k0 < DINW; k0 += 16) {
        int c0 = k0 + lk;
        float4 a;
        if (c0 < 400)      a = *(const float4*)(arow_w + c0);
        else if (c0 < 432) a = *(const float4*)(arow_c + (c0 - 400));
        else               a = *(const float4*)(arow_p + (c0 - 432));
        float4 b = *(const float4*)(B + (size_t)(n0 + lr) * DINW + c0);
        __syncthreads();
        As[lk + 0][lr] = a.x; As[lk + 1][lr] = a.y; As[lk + 2][lr] = a.z; As[lk + 3][lr] = a.w;
        Bs[lk + 0][lr] = b.x; Bs[lk + 1][lr] = b.y; Bs[lk + 2][lr] = b.z; Bs[lk + 3][lr] = b.w;
        __syncthreads();
        #pragma unroll
        for (int k = 0; k < 16; k++) {
            float4 av = *(const float4*)&As[k][ty * 4];
            float4 bv = *(const float4*)&Bs[k][tx * 4];
            float aa[4] = {av.x, av.y, av.z, av.w};
            float bb[4] = {bv.x, bv.y, bv.z, bv.w};
            #pragma unroll
            for (int i = 0; i < 4; i++)
                #pragma unroll
                for (int jj = 0; jj < 4; jj++)
                    acc[i][jj] += aa[i] * bb[jj];
        }
    }
    float4 bs4 = *(const float4*)(bias + n0 + tx * 4);
    float bb4[4] = {bs4.x, bs4.y, bs4.z, bs4.w};
    #pragma unroll
    for (int i = 0; i < 4; i++) {
        union { __hip_bfloat16 h[4]; ushort4 u; } cv;
        #pragma unroll
        for (int jj = 0; jj < 4; jj++)
            cv.h[jj] = __float2bfloat16(acc[i][jj] + bb4[jj]);
        *(ushort4*)(C + (size_t)(m0 + ty * 4 + i) * G4 + n0 + tx * 4) = cv.u;
    }
}

// ------------------------------------------------------- K3: LSTM recurrence
// grid = 2*NWG = 256 blocks of 384 threads (6 waves). dir=blockIdx&1, slot=blockIdx>>1.
// Wave wv owns h index j = slot*6+wv. Lane (q=lane>>4, gl=lane&15): gate q,
// column set {gl*4 + m*64 + e} (coalesced float4 across the 16-lane group).
// Whh rows live in 48 registers/lane. No LDS -> occupancy unconstrained;
// 256 blocks <= 256 CUs -> co-resident. Bounded spin bails cleanly on anomaly.
__global__ __launch_bounds__(384) void k_lstm(
    const __hip_bfloat16* __restrict__ xg_f, const __hip_bfloat16* __restrict__ xg_b,
    const float* __restrict__ Whh_f, const float* __restrict__ Whh_b,
    const float* __restrict__ h0, const float* __restrict__ c0v,
    float* __restrict__ hs_f, float* __restrict__ hs_b,
    unsigned* __restrict__ flags)
{
    int wg = blockIdx.x;
    int dir = wg & 1, slot = wg >> 1;
    const __hip_bfloat16* xg = dir ? xg_b : xg_f;
    const float* Whh = dir ? Whh_b : Whh_f;
    float* hs        = dir ? hs_b  : hs_f;
    unsigned* flg = flags + dir * NWG;

    int tid = threadIdx.x, lane = tid & 63, wv = tid >> 6;   // wv 0..5
    int q = lane >> 4, gl = lane & 15;
    int j = slot * JPW + wv;

    // load this lane's Whh slice into registers (row q*768+j, cols gl*4+m*64)
    float w[48];
    const float* wr = Whh + (size_t)(q * HDIM + j) * HDIM;
    #pragma unroll
    for (int m = 0; m < 12; m++) {
        float4 f4 = *(const float4*)(wr + gl * 4 + m * 64);
        w[m * 4 + 0] = f4.x; w[m * 4 + 1] = f4.y;
        w[m * 4 + 2] = f4.z; w[m * 4 + 3] = f4.w;
    }
    float cst = c0v[dir * HDIM + j];

    unsigned spins = 0;
    bool dead = false;
    for (int t = 0; t < SEQ; t++) {
        int xrow = dir ? (SEQ - 1 - t) : t;
        const __hip_bfloat16* xga = xg + (size_t)xrow * G4 + j;
        float xv0 = __bfloat162float(xga[0]);
        float xv1 = __bfloat162float(xga[HDIM]);
        float xv2 = __bfloat162float(xga[2 * HDIM]);
        float xv3 = __bfloat162float(xga[3 * HDIM]);

        if (t > 0) {
            unsigned need = (unsigned)t;
            int ok;
            do {
                unsigned fv = (tid < NWG)
                    ? __hip_atomic_load(&flg[tid], __ATOMIC_RELAXED, __HIP_MEMORY_SCOPE_AGENT)
                    : need;
                if (++spins > SPIN_LIMIT) { dead = true; fv = need; }  // uniform across block
                ok = (fv >= need);
            } while (!__syncthreads_and(ok));
            __builtin_amdgcn_fence(__ATOMIC_ACQUIRE, "agent");  // invalidate stale L1/L2
            if (dead) break;   // spins is block-uniform -> uniform break, no hang
        }

        const float* hsrc = (t == 0) ? (h0 + dir * HDIM)
                                     : (hs + (size_t)(dir ? (SEQ - t) : (t - 1)) * HDIM);
        float acc = 0.f;
        #pragma unroll
        for (int m = 0; m < 12; m++) {
            float4 f4 = *(const float4*)(hsrc + gl * 4 + m * 64);
            acc += w[m * 4 + 0] * f4.x + w[m * 4 + 1] * f4.y
                 + w[m * 4 + 2] * f4.z + w[m * 4 + 3] * f4.w;
        }
        acc += __shfl_xor(acc, 1);
        acc += __shfl_xor(acc, 2);
        acc += __shfl_xor(acc, 4);
        acc += __shfl_xor(acc, 8);
        float si = __shfl(acc, 0),  sf = __shfl(acc, 16);
        float sg = __shfl(acc, 32), so = __shfl(acc, 48);

        float gi = sigf(xv0 + si), gf = sigf(xv1 + sf);
        float gg = tanhf_fast(xv2 + sg), go = sigf(xv3 + so);
        cst = gf * cst + gi * gg;
        float h = go * tanhf_fast(cst);

        int hrow = dir ? (SEQ - 1 - t) : t;
        if (lane == 0)
            __hip_atomic_store(&hs[(size_t)hrow * HDIM + j], h,
                               __ATOMIC_RELAXED, __HIP_MEMORY_SCOPE_AGENT);  // write-through
        __syncthreads();  // all 6 waves' stores drained (vmcnt0) before publish
        if (tid == 0)
            __hip_atomic_store(&flg[slot], (unsigned)(t + 1),
                               __ATOMIC_RELAXED, __HIP_MEMORY_SCOPE_AGENT);
    }
}

// --------------------- K4: o = [hs_f,hs_b]@Wc^T + bc, log_softmax over C=13
__global__ __launch_bounds__(256) void k_head(
    const float* __restrict__ hs_f, const float* __restrict__ hs_b,
    const float* __restrict__ Wc, const float* __restrict__ bc,
    float* __restrict__ out)
{
    int tid = threadIdx.x, lane = tid & 63, wv = tid >> 6;
    int row = blockIdx.x * 4 + wv;
    const float* src = (lane < 32) ? (hs_f + (size_t)row * HDIM + lane * 24)
                                   : (hs_b + (size_t)row * HDIM + (lane - 32) * 24);
    float hvv[24];
    #pragma unroll
    for (int k = 0; k < 6; k++) {
        float4 f4 = *(const float4*)(src + k * 4);
        hvv[k * 4 + 0] = f4.x; hvv[k * 4 + 1] = f4.y;
        hvv[k * 4 + 2] = f4.z; hvv[k * 4 + 3] = f4.w;
    }
    int off = (lane < 32) ? lane * 24 : 768 + (lane - 32) * 24;
    float o[13];
    #pragma unroll
    for (int n = 0; n < CDIM; n++) {
        const float* wr2 = Wc + (size_t)n * 1536 + off;
        float s0 = 0.f, s1 = 0.f, s2 = 0.f, s3 = 0.f;
        #pragma unroll
        for (int k = 0; k < 6; k++) {
            float4 w4 = *(const float4*)(wr2 + k * 4);
            s0 += w4.x * hvv[k * 4 + 0];
            s1 += w4.y * hvv[k * 4 + 1];
            s2 += w4.z * hvv[k * 4 + 2];
            s3 += w4.w * hvv[k * 4 + 3];
        }
        o[n] = (s0 + s1) + (s2 + s3);
    }
    #pragma unroll
    for (int n = 0; n < CDIM; n++) {
        #pragma unroll
        for (int d = 1; d < 64; d <<= 1) o[n] += __shfl_xor(o[n], d);
        o[n] += bc[n];
    }
    float m = o[0];
    #pragma unroll
    for (int n = 1; n < CDIM; n++) m = fmaxf(m, o[n]);
    float sum = 0.f;
    #pragma unroll
    for (int n = 0; n < CDIM; n++) sum += __expf(o[n] - m);
    float ls = m + __logf(sum);
    if (lane == 0) {
        #pragma unroll
        for (int n = 0; n < CDIM; n++) out[(size_t)row * CDIM + n] = o[n] - ls;
    }
}

// ------------------------------------------------------------ K5: Viterbi
__global__ __launch_bounds__(64) void k_viterbi(
    const float* __restrict__ ts, const float* __restrict__ st,
    const float* __restrict__ en, const float* __restrict__ tr,
    float* __restrict__ tags_out)
{
    __shared__ unsigned char bp[SEQ - 1][16];
    __shared__ float sl[16];
    __shared__ unsigned char path[SEQ];
    int n = threadIdx.x;
    float trn[13];
    float score = 0.f;
    if (n < CDIM) {
        #pragma unroll
        for (int p = 0; p < CDIM; p++) trn[p] = tr[p * CDIM + n];
        score = st[n] + ts[n];
    }
    for (int s = 1; s < SEQ; s++) {
        if (n < CDIM) sl[n] = score;
        float em = (n < CDIM) ? ts[(size_t)s * CDIM + n] : 0.f;
        __syncthreads();
        if (n < CDIM) {
            float best = -1e30f; int arg = 0;
            #pragma unroll
            for (int p = 0; p < CDIM; p++) {
                float v = sl[p] + trn[p];
                if (v > best) { best = v; arg = p; }   // first-max, matches jnp.argmax
            }
            score = best + em;
            bp[s - 1][n] = (unsigned char)arg;
        }
        __syncthreads();
    }
    if (n < CDIM) sl[n] = score + en[n];
    __syncthreads();
    if (n == 0) {
        float best = -1e30f; int last = 0;
        for (int p = 0; p < CDIM; p++) { if (sl[p] > best) { best = sl[p]; last = p; } }
        int cur = last;
        path[SEQ - 1] = (unsigned char)cur;
        for (int s = SEQ - 2; s >= 0; s--) { cur = bp[s][cur]; path[s] = (unsigned char)cur; }
    }
    __syncthreads();
    for (int i = n; i < SEQ; i += 64) tags_out[i] = (float)path[i];
}

// --------------------------------------------- fallback if ws is too small
__global__ void k_zero(float* p, int n) {
    int i = blockIdx.x * 256 + threadIdx.x;
    if (i < n) p[i] = 0.f;
}

// ----------------------------------------------------------------- launch
extern "C" void kernel_launch(void* const* d_in, const int* in_sizes, int n_in,
                              void* d_out, int out_size, void* d_ws, size_t ws_size,
                              hipStream_t stream)
{
    const int*   x      = (const int*)d_in[0];
    const int*   casing = (const int*)d_in[1];
    const int*   pos    = (const int*)d_in[2];
    const float* we     = (const float*)d_in[3];
    const float* ce     = (const float*)d_in[4];
    const float* pe     = (const float*)d_in[5];
    const float* Wih_f  = (const float*)d_in[6];
    const float* Whh_f  = (const float*)d_in[7];
    const float* b_f    = (const float*)d_in[8];
    const float* Wih_b  = (const float*)d_in[9];
    const float* Whh_b  = (const float*)d_in[10];
    const float* b_b    = (const float*)d_in[11];
    const float* Wc     = (const float*)d_in[12];
    const float* bc     = (const float*)d_in[13];
    const float* strt   = (const float*)d_in[14];
    const float* endt   = (const float*)d_in[15];
    const float* trans  = (const float*)d_in[16];
    const float* h0     = (const float*)d_in[17];
    const float* c0     = (const float*)d_in[18];

    // ws layout (bytes):
    //   hs_f  fp32  2048*768*4 = 6,291,456      @ 0
    //   hs_b  fp32  6,291,456                   @ 6,291,456
    //   xg_f  bf16  2048*3072*2 = 12,582,912    @ 12,582,912
    //   xg_b  bf16  12,582,912                  @ 25,165,824
    //   flags u32   2*NWG*4 = 1,024             @ 37,748,736
    const size_t need = 37749760;
    if (ws_size < need) {   // clean deterministic failure instead of OOB fault
        k_zero<<<(out_size + 255) / 256, 256, 0, stream>>>((float*)d_out, out_size);
        return;
    }
    char* wsb = (char*)d_ws;
    float* hs_f = (float*)(wsb);
    float* hs_b = (float*)(wsb + 6291456);
    __hip_bfloat16* xg_f = (__hip_bfloat16*)(wsb + 12582912);
    __hip_bfloat16* xg_b = (__hip_bfloat16*)(wsb + 25165824);
    unsigned* flags = (unsigned*)(wsb + 37748736);

    hipMemsetAsync(flags, 0, 2 * NWG * sizeof(unsigned), stream);

    k_gemm_xg<<<dim3(G4 / 64, SEQ / 64, 2), 256, 0, stream>>>(
        x, casing, pos, we, ce, pe, Wih_f, b_f, Wih_b, b_b, xg_f, xg_b);
    k_lstm<<<2 * NWG, 384, 0, stream>>>(
        xg_f, xg_b, Whh_f, Whh_b, h0, c0, hs_f, hs_b, flags);
    k_head<<<SEQ / 4, 256, 0, stream>>>(hs_f, hs_b, Wc, bc, (float*)d_out);
    k_viterbi<<<1, 64, 0, stream>>>(
        (const float*)d_out, strt, endt, trans, (float*)d_out + (size_t)SEQ * CDIM);
}

// Round 3
// 8572.659 us; speedup vs baseline: 3.4820x; 3.4820x over previous
//
#include <hip/hip_runtime.h>
#include <hip/hip_bf16.h>

// BiLSTM-CRF tagger, MI355X. Round 3: tagged-word h exchange.
//   K2 fused embed-gather + xg GEMM (fp32 compute, bf16 store)
//   K3 LSTM recurrence: 256 blocks (128/dir) x 384 thr. Each wave owns one
//      h-element; Whh rows in 48 VGPRs/lane. Exchange protocol: producer
//      stores ONE 8-byte word {tag=t+1, f32 h} (agent-scope relaxed atomic,
//      double-buffered by step parity). Wave 0 of each block polls the 768
//      words (12 coalesced dwordx2/lane), drops fp32 h into LDS, bumps an
//      LDS flag; waves 1..5 spin on the LDS flag. No fences, no flag array,
//      no block-wide barriers in the loop.
//   K4 head + log_softmax -> K5 Viterbi.

#define SEQ  2048
#define DINW 496
#define HDIM 768
#define G4   3072
#define CDIM 13
#define NWG  128          // workgroups per direction (2*NWG = 256 blocks)
#define JPW  6            // h elements per workgroup
#define SPIN_LIMIT (1u << 20)
#define DEADBIT 0x40000000u

__device__ __forceinline__ float sigf(float x) { return 1.0f / (1.0f + __expf(-x)); }
__device__ __forceinline__ float tanhf_fast(float x) {
    float ax = fabsf(x);
    float e  = __expf(-2.0f * ax);
    float t  = (1.0f - e) / (1.0f + e);
    return copysignf(t, x);
}

// ---------------- K2: xg = [we[x],ce[casing],pe[pos]] @ Wih^T + b  (bf16 out)
__global__ __launch_bounds__(256) void k_gemm_xg(
    const int* __restrict__ x, const int* __restrict__ casing, const int* __restrict__ pos,
    const float* __restrict__ we, const float* __restrict__ ce, const float* __restrict__ pe,
    const float* __restrict__ Wih_f, const float* __restrict__ b_f,
    const float* __restrict__ Wih_b, const float* __restrict__ b_b,
    __hip_bfloat16* __restrict__ xg_f, __hip_bfloat16* __restrict__ xg_b)
{
    __shared__ float As[16][68];
    __shared__ float Bs[16][68];
    int dir = blockIdx.z;
    const float* B    = dir ? Wih_b : Wih_f;
    const float* bias = dir ? b_b   : b_f;
    __hip_bfloat16* C = dir ? xg_b  : xg_f;
    int n0 = blockIdx.x * 64, m0 = blockIdx.y * 64;
    int tid = threadIdx.x;
    int tx = tid & 15, ty = tid >> 4;
    int lr = tid >> 2, lk = (tid & 3) * 4;

    int m = m0 + lr;
    const float* arow_w = we + (size_t)x[m] * 400;
    const float* arow_c = ce + (size_t)casing[m] * 32;
    const float* arow_p = pe + (size_t)pos[m] * 64;

    float acc[4][4] = {};
    for (int k0 = 0; k0 < DINW; k0 += 16) {
        int c0 = k0 + lk;
        float4 a;
        if (c0 < 400)      a = *(const float4*)(arow_w + c0);
        else if (c0 < 432) a = *(const float4*)(arow_c + (c0 - 400));
        else               a = *(const float4*)(arow_p + (c0 - 432));
        float4 b = *(const float4*)(B + (size_t)(n0 + lr) * DINW + c0);
        __syncthreads();
        As[lk + 0][lr] = a.x; As[lk + 1][lr] = a.y; As[lk + 2][lr] = a.z; As[lk + 3][lr] = a.w;
        Bs[lk + 0][lr] = b.x; Bs[lk + 1][lr] = b.y; Bs[lk + 2][lr] = b.z; Bs[lk + 3][lr] = b.w;
        __syncthreads();
        #pragma unroll
        for (int k = 0; k < 16; k++) {
            float4 av = *(const float4*)&As[k][ty * 4];
            float4 bv = *(const float4*)&Bs[k][tx * 4];
            float aa[4] = {av.x, av.y, av.z, av.w};
            float bb[4] = {bv.x, bv.y, bv.z, bv.w};
            #pragma unroll
            for (int i = 0; i < 4; i++)
                #pragma unroll
                for (int jj = 0; jj < 4; jj++)
                    acc[i][jj] += aa[i] * bb[jj];
        }
    }
    float4 bs4 = *(const float4*)(bias + n0 + tx * 4);
    float bb4[4] = {bs4.x, bs4.y, bs4.z, bs4.w};
    #pragma unroll
    for (int i = 0; i < 4; i++) {
        union { __hip_bfloat16 h[4]; ushort4 u; } cv;
        #pragma unroll
        for (int jj = 0; jj < 4; jj++)
            cv.h[jj] = __float2bfloat16(acc[i][jj] + bb4[jj]);
        *(ushort4*)(C + (size_t)(m0 + ty * 4 + i) * G4 + n0 + tx * 4) = cv.u;
    }
}

// ------------------------------------------------------- K3: LSTM recurrence
// msg layout: msg[dir][parity][768] u64 words {tag<<32 | f32bits(h)}.
// h(t) stored with tag t+1 into parity t&1. Consumer at step t needs tag t in
// parity (t&1)^1. Overwrite (t+2 steps later) provably safe: all-to-all
// consumption bounds inter-wave lag to <2 steps.
__global__ __launch_bounds__(384) void k_lstm(
    const __hip_bfloat16* __restrict__ xg_f, const __hip_bfloat16* __restrict__ xg_b,
    const float* __restrict__ Whh_f, const float* __restrict__ Whh_b,
    const float* __restrict__ h0, const float* __restrict__ c0v,
    float* __restrict__ hs_f, float* __restrict__ hs_b,
    unsigned long long* __restrict__ msg)
{
    __shared__ float hbuf[2][HDIM];
    __shared__ unsigned lflag;

    int wg = blockIdx.x;
    int dir = wg & 1, slot = wg >> 1;
    const __hip_bfloat16* xg = dir ? xg_b : xg_f;
    const float* Whh = dir ? Whh_b : Whh_f;
    float* hs        = dir ? hs_b  : hs_f;
    unsigned long long* mdir = msg + (size_t)dir * 2 * HDIM;

    int tid = threadIdx.x, lane = tid & 63, wv = tid >> 6;   // wv 0..5
    int q = lane >> 4, gl = lane & 15;
    int j = slot * JPW + wv;

    // this lane's Whh slice: row q*768+j, cols gl*4 + m*64 + e
    float w[48];
    const float* wr = Whh + (size_t)(q * HDIM + j) * HDIM;
    #pragma unroll
    for (int m = 0; m < 12; m++) {
        float4 f4 = *(const float4*)(wr + gl * 4 + m * 64);
        w[m * 4 + 0] = f4.x; w[m * 4 + 1] = f4.y;
        w[m * 4 + 2] = f4.z; w[m * 4 + 3] = f4.w;
    }
    float cst = c0v[dir * HDIM + j];

    if (tid == 0) lflag = 0;
    __syncthreads();

    for (int t = 0; t < SEQ; t++) {
        int xrow = dir ? (SEQ - 1 - t) : t;
        const __hip_bfloat16* xga = xg + (size_t)xrow * G4 + j;
        float xv0 = __bfloat162float(xga[0]);
        float xv1 = __bfloat162float(xga[HDIM]);
        float xv2 = __bfloat162float(xga[2 * HDIM]);
        float xv3 = __bfloat162float(xga[3 * HDIM]);

        int par = (t & 1) ^ 1;   // parity slot holding h(t-1)

        if (wv == 0) {
            bool dead = false;
            if (t == 0) {
                #pragma unroll
                for (int m = 0; m < 12; m++)
                    hbuf[1][m * 64 + lane] = h0[dir * HDIM + m * 64 + lane];
            } else {
                const unsigned long long* g = mdir + (size_t)par * HDIM;
                unsigned long long vals[12];
                unsigned iter = 0;
                bool ok;
                do {
                    ok = true;
                    #pragma unroll
                    for (int m = 0; m < 12; m++)
                        vals[m] = __hip_atomic_load(&g[m * 64 + lane],
                                                    __ATOMIC_RELAXED, __HIP_MEMORY_SCOPE_AGENT);
                    #pragma unroll
                    for (int m = 0; m < 12; m++)
                        ok &= ((unsigned)(vals[m] >> 32) == (unsigned)t);
                    ok = __all(ok);
                } while (!ok && ++iter < SPIN_LIMIT);
                if (!ok) dead = true;
                #pragma unroll
                for (int m = 0; m < 12; m++) {
                    union { unsigned u; float f; } cvt;
                    cvt.u = (unsigned)vals[m];
                    hbuf[par][m * 64 + lane] = cvt.f;
                }
            }
            __threadfence_block();   // hbuf writes visible before flag bump
            if (lane == 0)
                __hip_atomic_store(&lflag, (unsigned)(t + 1) | (dead ? DEADBIT : 0u),
                                   __ATOMIC_RELAXED, __HIP_MEMORY_SCOPE_WORKGROUP);
        }

        unsigned f;
        do {
            f = __hip_atomic_load(&lflag, __ATOMIC_RELAXED, __HIP_MEMORY_SCOPE_WORKGROUP);
        } while ((f & ~DEADBIT) < (unsigned)(t + 1));
        if (f & DEADBIT) break;   // bounded-spin bail: terminate, fail visibly

        // matvec slice: acc over this lane's 48 columns from LDS
        float acc = 0.f;
        #pragma unroll
        for (int m = 0; m < 12; m++) {
            float4 f4 = *(const float4*)&hbuf[par][gl * 4 + m * 64];
            acc += w[m * 4 + 0] * f4.x + w[m * 4 + 1] * f4.y
                 + w[m * 4 + 2] * f4.z + w[m * 4 + 3] * f4.w;
        }
        acc += __shfl_xor(acc, 1);
        acc += __shfl_xor(acc, 2);
        acc += __shfl_xor(acc, 4);
        acc += __shfl_xor(acc, 8);
        float si = __shfl(acc, 0),  sf = __shfl(acc, 16);
        float sg = __shfl(acc, 32), so = __shfl(acc, 48);

        float gi = sigf(xv0 + si), gf = sigf(xv1 + sf);
        float gg = tanhf_fast(xv2 + sg), go = sigf(xv3 + so);
        cst = gf * cst + gi * gg;
        float h = go * tanhf_fast(cst);

        if (lane == 0) {
            int hrow = dir ? (SEQ - 1 - t) : t;
            hs[(size_t)hrow * HDIM + j] = h;          // for K4 (cross-dispatch)
            union { float f; unsigned u; } cvt; cvt.f = h;
            unsigned long long word = ((unsigned long long)(unsigned)(t + 1) << 32)
                                    | (unsigned long long)cvt.u;
            __hip_atomic_store(&mdir[(size_t)(t & 1) * HDIM + j], word,
                               __ATOMIC_RELAXED, __HIP_MEMORY_SCOPE_AGENT);
        }
    }
}

// --------------------- K4: o = [hs_f,hs_b]@Wc^T + bc, log_softmax over C=13
__global__ __launch_bounds__(256) void k_head(
    const float* __restrict__ hs_f, const float* __restrict__ hs_b,
    const float* __restrict__ Wc, const float* __restrict__ bc,
    float* __restrict__ out)
{
    int tid = threadIdx.x, lane = tid & 63, wv = tid >> 6;
    int row = blockIdx.x * 4 + wv;
    const float* src = (lane < 32) ? (hs_f + (size_t)row * HDIM + lane * 24)
                                   : (hs_b + (size_t)row * HDIM + (lane - 32) * 24);
    float hvv[24];
    #pragma unroll
    for (int k = 0; k < 6; k++) {
        float4 f4 = *(const float4*)(src + k * 4);
        hvv[k * 4 + 0] = f4.x; hvv[k * 4 + 1] = f4.y;
        hvv[k * 4 + 2] = f4.z; hvv[k * 4 + 3] = f4.w;
    }
    int off = (lane < 32) ? lane * 24 : 768 + (lane - 32) * 24;
    float o[13];
    #pragma unroll
    for (int n = 0; n < CDIM; n++) {
        const float* wr2 = Wc + (size_t)n * 1536 + off;
        float s0 = 0.f, s1 = 0.f, s2 = 0.f, s3 = 0.f;
        #pragma unroll
        for (int k = 0; k < 6; k++) {
            float4 w4 = *(const float4*)(wr2 + k * 4);
            s0 += w4.x * hvv[k * 4 + 0];
            s1 += w4.y * hvv[k * 4 + 1];
            s2 += w4.z * hvv[k * 4 + 2];
            s3 += w4.w * hvv[k * 4 + 3];
        }
        o[n] = (s0 + s1) + (s2 + s3);
    }
    #pragma unroll
    for (int n = 0; n < CDIM; n++) {
        #pragma unroll
        for (int d = 1; d < 64; d <<= 1) o[n] += __shfl_xor(o[n], d);
        o[n] += bc[n];
    }
    float m = o[0];
    #pragma unroll
    for (int n = 1; n < CDIM; n++) m = fmaxf(m, o[n]);
    float sum = 0.f;
    #pragma unroll
    for (int n = 0; n < CDIM; n++) sum += __expf(o[n] - m);
    float ls = m + __logf(sum);
    if (lane == 0) {
        #pragma unroll
        for (int n = 0; n < CDIM; n++) out[(size_t)row * CDIM + n] = o[n] - ls;
    }
}

// ------------------------------------------------------------ K5: Viterbi
__global__ __launch_bounds__(64) void k_viterbi(
    const float* __restrict__ ts, const float* __restrict__ st,
    const float* __restrict__ en, const float* __restrict__ tr,
    float* __restrict__ tags_out)
{
    __shared__ unsigned char bp[SEQ - 1][16];
    __shared__ float sl[16];
    __shared__ unsigned char path[SEQ];
    int n = threadIdx.x;
    float trn[13];
    float score = 0.f;
    if (n < CDIM) {
        #pragma unroll
        for (int p = 0; p < CDIM; p++) trn[p] = tr[p * CDIM + n];
        score = st[n] + ts[n];
    }
    for (int s = 1; s < SEQ; s++) {
        if (n < CDIM) sl[n] = score;
        float em = (n < CDIM) ? ts[(size_t)s * CDIM + n] : 0.f;
        __syncthreads();
        if (n < CDIM) {
            float best = -1e30f; int arg = 0;
            #pragma unroll
            for (int p = 0; p < CDIM; p++) {
                float v = sl[p] + trn[p];
                if (v > best) { best = v; arg = p; }   // first-max, matches jnp.argmax
            }
            score = best + em;
            bp[s - 1][n] = (unsigned char)arg;
        }
        __syncthreads();
    }
    if (n < CDIM) sl[n] = score + en[n];
    __syncthreads();
    if (n == 0) {
        float best = -1e30f; int last = 0;
        for (int p = 0; p < CDIM; p++) { if (sl[p] > best) { best = sl[p]; last = p; } }
        int cur = last;
        path[SEQ - 1] = (unsigned char)cur;
        for (int s = SEQ - 2; s >= 0; s--) { cur = bp[s][cur]; path[s] = (unsigned char)cur; }
    }
    __syncthreads();
    for (int i = n; i < SEQ; i += 64) tags_out[i] = (float)path[i];
}

// --------------------------------------------- fallback if ws is too small
__global__ void k_zero(float* p, int n) {
    int i = blockIdx.x * 256 + threadIdx.x;
    if (i < n) p[i] = 0.f;
}

// ----------------------------------------------------------------- launch
extern "C" void kernel_launch(void* const* d_in, const int* in_sizes, int n_in,
                              void* d_out, int out_size, void* d_ws, size_t ws_size,
                              hipStream_t stream)
{
    const int*   x      = (const int*)d_in[0];
    const int*   casing = (const int*)d_in[1];
    const int*   pos    = (const int*)d_in[2];
    const float* we     = (const float*)d_in[3];
    const float* ce     = (const float*)d_in[4];
    const float* pe     = (const float*)d_in[5];
    const float* Wih_f  = (const float*)d_in[6];
    const float* Whh_f  = (const float*)d_in[7];
    const float* b_f    = (const float*)d_in[8];
    const float* Wih_b  = (const float*)d_in[9];
    const float* Whh_b  = (const float*)d_in[10];
    const float* b_b    = (const float*)d_in[11];
    const float* Wc     = (const float*)d_in[12];
    const float* bc     = (const float*)d_in[13];
    const float* strt   = (const float*)d_in[14];
    const float* endt   = (const float*)d_in[15];
    const float* trans  = (const float*)d_in[16];
    const float* h0     = (const float*)d_in[17];
    const float* c0     = (const float*)d_in[18];

    // ws layout (bytes):
    //   hs_f fp32 6,291,456 @ 0
    //   hs_b fp32 6,291,456 @ 6,291,456
    //   xg_f bf16 12,582,912 @ 12,582,912
    //   xg_b bf16 12,582,912 @ 25,165,824
    //   msg  u64  2*2*768*8 = 24,576 @ 37,748,736
    const size_t need = 37748736 + 24576;
    if (ws_size < need) {   // clean deterministic failure instead of OOB fault
        k_zero<<<(out_size + 255) / 256, 256, 0, stream>>>((float*)d_out, out_size);
        return;
    }
    char* wsb = (char*)d_ws;
    float* hs_f = (float*)(wsb);
    float* hs_b = (float*)(wsb + 6291456);
    __hip_bfloat16* xg_f = (__hip_bfloat16*)(wsb + 12582912);
    __hip_bfloat16* xg_b = (__hip_bfloat16*)(wsb + 25165824);
    unsigned long long* msg = (unsigned long long*)(wsb + 37748736);

    hipMemsetAsync(msg, 0, 24576, stream);   // reset tags every call (replay-safe)

    k_gemm_xg<<<dim3(G4 / 64, SEQ / 64, 2), 256, 0, stream>>>(
        x, casing, pos, we, ce, pe, Wih_f, b_f, Wih_b, b_b, xg_f, xg_b);
    k_lstm<<<2 * NWG, 384, 0, stream>>>(
        xg_f, xg_b, Whh_f, Whh_b, h0, c0, hs_f, hs_b, msg);
    k_head<<<SEQ / 4, 256, 0, stream>>>(hs_f, hs_b, Wc, bc, (float*)d_out);
    k_viterbi<<<1, 64, 0, stream>>>(
        (const float*)d_out, strt, endt, trans, (float*)d_out + (size_t)SEQ * CDIM);
}

// Round 7
// 7272.410 us; speedup vs baseline: 4.1046x; 1.1788x over previous
//
#include <hip/hip_runtime.h>
#include <hip/hip_bf16.h>

// BiLSTM-CRF tagger, MI355X. Round 7: resubmit of round-6 (infra flake x2 on
// the same pod; kernel never reached the device). Protocol recap:
//   K2 fused embed-gather + xg GEMM (fp32 compute, bf16 store)
//   K3 LSTM recurrence: 96 blocks (48/dir) x 1024 thr (16 waves, 1 h-elem/wave).
//      Producers store tagged u64 {tag,f32 h} (parity double-buffer) + a u32
//      monotone step counter per block (>= compare: wrap/fast-producer safe --
//      this is the fix for round 4's exact-match hint race).
//      Wave 0 polls hints, burst-reads the 768 tagged words, verifies tags
//      exactly (deadlock-free via the all-to-all gate), LDS-broadcasts.
//      Hardening: tight spin bounds + global abort broadcast -> any anomaly
//      terminates the whole grid in ~1 spin-round (no long-running kernel).
//   K4 head + log_softmax -> K5 wave-synchronous Viterbi.

#define SEQ  2048
#define DINW 496
#define HDIM 768
#define G4   3072
#define CDIM 13
#define NWG  48           // workgroups per direction (2*NWG = 96 blocks)
#define JPW  16           // h elements per workgroup (one per wave)
#define HINT_SPIN (1u << 16)
#define DATA_SPIN (1u << 14)
#define DEADBIT 0x40000000u

__device__ __forceinline__ float sigf(float x) { return 1.0f / (1.0f + __expf(-x)); }
__device__ __forceinline__ float tanhf_fast(float x) {
    float ax = fabsf(x);
    float e  = __expf(-2.0f * ax);
    float t  = (1.0f - e) / (1.0f + e);
    return copysignf(t, x);
}

// ---------------- K2: xg = [we[x],ce[casing],pe[pos]] @ Wih^T + b  (bf16 out)
__global__ __launch_bounds__(256) void k_gemm_xg(
    const int* __restrict__ x, const int* __restrict__ casing, const int* __restrict__ pos,
    const float* __restrict__ we, const float* __restrict__ ce, const float* __restrict__ pe,
    const float* __restrict__ Wih_f, const float* __restrict__ b_f,
    const float* __restrict__ Wih_b, const float* __restrict__ b_b,
    __hip_bfloat16* __restrict__ xg_f, __hip_bfloat16* __restrict__ xg_b)
{
    __shared__ float As[16][68];
    __shared__ float Bs[16][68];
    int dir = blockIdx.z;
    const float* B    = dir ? Wih_b : Wih_f;
    const float* bias = dir ? b_b   : b_f;
    __hip_bfloat16* C = dir ? xg_b  : xg_f;
    int n0 = blockIdx.x * 64, m0 = blockIdx.y * 64;
    int tid = threadIdx.x;
    int tx = tid & 15, ty = tid >> 4;
    int lr = tid >> 2, lk = (tid & 3) * 4;

    int m = m0 + lr;
    const float* arow_w = we + (size_t)x[m] * 400;
    const float* arow_c = ce + (size_t)casing[m] * 32;
    const float* arow_p = pe + (size_t)pos[m] * 64;

    float acc[4][4] = {};
    for (int k0 = 0; k0 < DINW; k0 += 16) {
        int c0 = k0 + lk;
        float4 a;
        if (c0 < 400)      a = *(const float4*)(arow_w + c0);
        else if (c0 < 432) a = *(const float4*)(arow_c + (c0 - 400));
        else               a = *(const float4*)(arow_p + (c0 - 432));
        float4 b = *(const float4*)(B + (size_t)(n0 + lr) * DINW + c0);
        __syncthreads();
        As[lk + 0][lr] = a.x; As[lk + 1][lr] = a.y; As[lk + 2][lr] = a.z; As[lk + 3][lr] = a.w;
        Bs[lk + 0][lr] = b.x; Bs[lk + 1][lr] = b.y; Bs[lk + 2][lr] = b.z; Bs[lk + 3][lr] = b.w;
        __syncthreads();
        #pragma unroll
        for (int k = 0; k < 16; k++) {
            float4 av = *(const float4*)&As[k][ty * 4];
            float4 bv = *(const float4*)&Bs[k][tx * 4];
            float aa[4] = {av.x, av.y, av.z, av.w};
            float bb[4] = {bv.x, bv.y, bv.z, bv.w};
            #pragma unroll
            for (int i = 0; i < 4; i++)
                #pragma unroll
                for (int jj = 0; jj < 4; jj++)
                    acc[i][jj] += aa[i] * bb[jj];
        }
    }
    float4 bs4 = *(const float4*)(bias + n0 + tx * 4);
    float bb4[4] = {bs4.x, bs4.y, bs4.z, bs4.w};
    #pragma unroll
    for (int i = 0; i < 4; i++) {
        union { __hip_bfloat16 h[4]; ushort4 u; } cv;
        #pragma unroll
        for (int jj = 0; jj < 4; jj++)
            cv.h[jj] = __float2bfloat16(acc[i][jj] + bb4[jj]);
        *(ushort4*)(C + (size_t)(m0 + ty * 4 + i) * G4 + n0 + tx * 4) = cv.u;
    }
}

// ------------------------------------------------------- K3: LSTM recurrence
// msg[dir][parity][768] u64 {tag<<32 | f32bits(h)}: h(t) -> parity t&1, tag t+1.
// done[dir*64 + slot] u32 = t+1 after block finishes step t (monotone, >= poll).
// Exact data-tag match is deadlock-free: tag t (parity (t-1)&1) is only
// overwritten by tag t+2 when its producer reaches step t+1, which requires
// every block to have consumed tag t+1, which requires every block to have
// consumed tag t first. So no reader can be starved of the tag it polls for.
__global__ __launch_bounds__(1024) void k_lstm(
    const __hip_bfloat16* __restrict__ xg_f, const __hip_bfloat16* __restrict__ xg_b,
    const float* __restrict__ Whh_f, const float* __restrict__ Whh_b,
    const float* __restrict__ h0, const float* __restrict__ c0v,
    float* __restrict__ hs_f, float* __restrict__ hs_b,
    unsigned long long* __restrict__ msg, unsigned* __restrict__ done,
    unsigned* __restrict__ abortw)
{
    __shared__ float hbuf[2][HDIM];
    __shared__ unsigned lflag;

    int wg = blockIdx.x;
    int dir = wg & 1, slot = wg >> 1;          // slot 0..47
    const __hip_bfloat16* xg = dir ? xg_b : xg_f;
    const float* Whh = dir ? Whh_b : Whh_f;
    float* hs        = dir ? hs_b  : hs_f;
    unsigned long long* mdir = msg + (size_t)dir * 2 * HDIM;
    unsigned* ddir = done + dir * 64;

    int tid = threadIdx.x, lane = tid & 63, wv = tid >> 6;   // wv 0..15
    int q = lane >> 4, gl = lane & 15;
    int j = slot * JPW + wv;

    // this lane's Whh slice: row q*768+j, cols gl*4 + m*64 + e
    float w[48];
    const float* wr = Whh + (size_t)(q * HDIM + j) * HDIM;
    #pragma unroll
    for (int m = 0; m < 12; m++) {
        float4 f4 = *(const float4*)(wr + gl * 4 + m * 64);
        w[m * 4 + 0] = f4.x; w[m * 4 + 1] = f4.y;
        w[m * 4 + 2] = f4.z; w[m * 4 + 3] = f4.w;
    }
    float cst = c0v[dir * HDIM + j];

    if (tid == 0) lflag = 0;
    __syncthreads();

    for (int t = 0; t < SEQ; t++) {
        int xrow = dir ? (SEQ - 1 - t) : t;
        const __hip_bfloat16* xga = xg + (size_t)xrow * G4 + j;
        float xv0 = __bfloat162float(xga[0]);
        float xv1 = __bfloat162float(xga[HDIM]);
        float xv2 = __bfloat162float(xga[2 * HDIM]);
        float xv3 = __bfloat162float(xga[3 * HDIM]);

        int par = (t & 1) ^ 1;   // parity slot holding h(t-1)

        if (wv == 0) {
            bool dead = false;
            if (t == 0) {
                #pragma unroll
                for (int m = 0; m < 12; m++)
                    hbuf[1][m * 64 + lane] = h0[dir * HDIM + m * 64 + lane];
            } else {
                // 1) poll hint lines: all blocks finished step t-1 (>= t);
                //    also watch the abort word.
                int bidx = (lane < NWG) ? lane : 0;
                unsigned iter = 0;
                bool hok;
                do {
                    unsigned v = __hip_atomic_load(&ddir[bidx],
                                    __ATOMIC_RELAXED, __HIP_MEMORY_SCOPE_AGENT);
                    unsigned ab = __hip_atomic_load(abortw,
                                    __ATOMIC_RELAXED, __HIP_MEMORY_SCOPE_AGENT);
                    if (ab) { dead = true; break; }
                    hok = __all((lane < NWG) ? (v >= (unsigned)t) : true);
                } while (!hok && ++iter < HINT_SPIN);
                if (!dead && !hok) dead = true;
                // 2) one-shot burst + exact tag verify (authoritative), rare retry
                if (!dead) {
                    const unsigned long long* g = mdir + (size_t)par * HDIM;
                    unsigned long long vals[12];
                    unsigned iter2 = 0;
                    bool ok;
                    do {
                        ok = true;
                        #pragma unroll
                        for (int m = 0; m < 12; m++)
                            vals[m] = __hip_atomic_load(&g[m * 64 + lane],
                                                        __ATOMIC_RELAXED, __HIP_MEMORY_SCOPE_AGENT);
                        #pragma unroll
                        for (int m = 0; m < 12; m++)
                            ok &= ((unsigned)(vals[m] >> 32) == (unsigned)t);
                        ok = __all(ok);
                    } while (!ok && ++iter2 < DATA_SPIN);
                    if (!ok) dead = true;
                    #pragma unroll
                    for (int m = 0; m < 12; m++) {
                        union { unsigned u; float f; } cvt;
                        cvt.u = (unsigned)vals[m];
                        hbuf[par][m * 64 + lane] = cvt.f;
                    }
                }
                if (dead && lane == 0) {   // cascade shutdown
                    __hip_atomic_store(abortw, 1u,
                                       __ATOMIC_RELAXED, __HIP_MEMORY_SCOPE_AGENT);
                    __hip_atomic_store(&ddir[slot], 0x7FFFFFFFu,
                                       __ATOMIC_RELAXED, __HIP_MEMORY_SCOPE_AGENT);
                }
            }
            __threadfence_block();   // hbuf visible before flag bump
            if (lane == 0)
                __hip_atomic_store(&lflag, (unsigned)(t + 1) | (dead ? DEADBIT : 0u),
                                   __ATOMIC_RELAXED, __HIP_MEMORY_SCOPE_WORKGROUP);
        }

        unsigned f;
        do {
            f = __hip_atomic_load(&lflag, __ATOMIC_RELAXED, __HIP_MEMORY_SCOPE_WORKGROUP);
        } while ((f & ~DEADBIT) < (unsigned)(t + 1));
        if (f & DEADBIT) break;   // bounded bail: terminate, fail visibly

        // matvec slice over this lane's 48 columns from LDS
        float acc = 0.f;
        #pragma unroll
        for (int m = 0; m < 12; m++) {
            float4 f4 = *(const float4*)&hbuf[par][gl * 4 + m * 64];
            acc += w[m * 4 + 0] * f4.x + w[m * 4 + 1] * f4.y
                 + w[m * 4 + 2] * f4.z + w[m * 4 + 3] * f4.w;
        }
        acc += __shfl_xor(acc, 1);
        acc += __shfl_xor(acc, 2);
        acc += __shfl_xor(acc, 4);
        acc += __shfl_xor(acc, 8);
        float si = __shfl(acc, 0),  sf = __shfl(acc, 16);
        float sg = __shfl(acc, 32), so = __shfl(acc, 48);

        float gi = sigf(xv0 + si), gf = sigf(xv1 + sf);
        float gg = tanhf_fast(xv2 + sg), go = sigf(xv3 + so);
        cst = gf * cst + gi * gg;
        float h = go * tanhf_fast(cst);

        if (lane == 0) {
            int hrow = dir ? (SEQ - 1 - t) : t;
            hs[(size_t)hrow * HDIM + j] = h;          // for K4 (cross-dispatch)
            union { float f; unsigned u; } cvt; cvt.f = h;
            unsigned long long word = ((unsigned long long)(unsigned)(t + 1) << 32)
                                    | (unsigned long long)cvt.u;
            __hip_atomic_store(&mdir[(size_t)(t & 1) * HDIM + j], word,
                               __ATOMIC_RELAXED, __HIP_MEMORY_SCOPE_AGENT);
            if (wv == 0)   // hint: monotone step counter for this block
                __hip_atomic_store(&ddir[slot], (unsigned)(t + 1),
                                   __ATOMIC_RELAXED, __HIP_MEMORY_SCOPE_AGENT);
        }
    }
}

// --------------------- K4: o = [hs_f,hs_b]@Wc^T + bc, log_softmax over C=13
__global__ __launch_bounds__(256) void k_head(
    const float* __restrict__ hs_f, const float* __restrict__ hs_b,
    const float* __restrict__ Wc, const float* __restrict__ bc,
    float* __restrict__ out)
{
    int tid = threadIdx.x, lane = tid & 63, wv = tid >> 6;
    int row = blockIdx.x * 4 + wv;
    const float* src = (lane < 32) ? (hs_f + (size_t)row * HDIM + lane * 24)
                                   : (hs_b + (size_t)row * HDIM + (lane - 32) * 24);
    float hvv[24];
    #pragma unroll
    for (int k = 0; k < 6; k++) {
        float4 f4 = *(const float4*)(src + k * 4);
        hvv[k * 4 + 0] = f4.x; hvv[k * 4 + 1] = f4.y;
        hvv[k * 4 + 2] = f4.z; hvv[k * 4 + 3] = f4.w;
    }
    int off = (lane < 32) ? lane * 24 : 768 + (lane - 32) * 24;
    float o[13];
    #pragma unroll
    for (int n = 0; n < CDIM; n++) {
        const float* wr2 = Wc + (size_t)n * 1536 + off;
        float s0 = 0.f, s1 = 0.f, s2 = 0.f, s3 = 0.f;
        #pragma unroll
        for (int k = 0; k < 6; k++) {
            float4 w4 = *(const float4*)(wr2 + k * 4);
            s0 += w4.x * hvv[k * 4 + 0];
            s1 += w4.y * hvv[k * 4 + 1];
            s2 += w4.z * hvv[k * 4 + 2];
            s3 += w4.w * hvv[k * 4 + 3];
        }
        o[n] = (s0 + s1) + (s2 + s3);
    }
    #pragma unroll
    for (int n = 0; n < CDIM; n++) {
        #pragma unroll
        for (int d = 1; d < 64; d <<= 1) o[n] += __shfl_xor(o[n], d);
        o[n] += bc[n];
    }
    float m = o[0];
    #pragma unroll
    for (int n = 1; n < CDIM; n++) m = fmaxf(m, o[n]);
    float sum = 0.f;
    #pragma unroll
    for (int n = 0; n < CDIM; n++) sum += __expf(o[n] - m);
    float ls = m + __logf(sum);
    if (lane == 0) {
        #pragma unroll
        for (int n = 0; n < CDIM; n++) out[(size_t)row * CDIM + n] = o[n] - ls;
    }
}

// ------------------------------------ K5: Viterbi, single wave, shuffle-based
__global__ __launch_bounds__(64) void k_viterbi(
    const float* __restrict__ ts, const float* __restrict__ st,
    const float* __restrict__ en, const float* __restrict__ tr,
    float* __restrict__ tags_out)
{
    __shared__ unsigned char bp[SEQ - 1][16];
    __shared__ unsigned char path[SEQ];
    int n = threadIdx.x;
    bool act = n < CDIM;
    float trn[CDIM];
    #pragma unroll
    for (int p = 0; p < CDIM; p++) trn[p] = act ? tr[p * CDIM + n] : -1e30f;
    float score = act ? (st[n] + ts[n]) : -1e30f;

    for (int s = 1; s < SEQ; s++) {
        float em = act ? ts[(size_t)s * CDIM + n] : 0.f;
        float sp[CDIM];
        #pragma unroll
        for (int p = 0; p < CDIM; p++) sp[p] = __shfl(score, p);
        float best = -1e30f; int arg = 0;
        #pragma unroll
        for (int p = 0; p < CDIM; p++) {
            float v = sp[p] + trn[p];
            if (v > best) { best = v; arg = p; }   // strict > keeps FIRST max
        }
        score = best + em;
        if (act) bp[s - 1][n] = (unsigned char)arg;
    }
    float fin = act ? (score + en[n]) : -1e30f;
    float fv[CDIM];
    #pragma unroll
    for (int p = 0; p < CDIM; p++) fv[p] = __shfl(fin, p);
    __syncthreads();           // bp writes visible to lane 0 (one wave: cheap)
    if (n == 0) {
        float best = -1e30f; int last = 0;
        #pragma unroll
        for (int p = 0; p < CDIM; p++) { if (fv[p] > best) { best = fv[p]; last = p; } }
        int cur = last;
        path[SEQ - 1] = (unsigned char)cur;
        for (int s = SEQ - 2; s >= 0; s--) { cur = bp[s][cur]; path[s] = (unsigned char)cur; }
    }
    __syncthreads();
    for (int i = n; i < SEQ; i += 64) tags_out[i] = (float)path[i];
}

// --------------------------------------------- fallback if ws is too small
__global__ void k_zero(float* p, int n) {
    int i = blockIdx.x * 256 + threadIdx.x;
    if (i < n) p[i] = 0.f;
}

// ----------------------------------------------------------------- launch
extern "C" void kernel_launch(void* const* d_in, const int* in_sizes, int n_in,
                              void* d_out, int out_size, void* d_ws, size_t ws_size,
                              hipStream_t stream)
{
    const int*   x      = (const int*)d_in[0];
    const int*   casing = (const int*)d_in[1];
    const int*   pos    = (const int*)d_in[2];
    const float* we     = (const float*)d_in[3];
    const float* ce     = (const float*)d_in[4];
    const float* pe     = (const float*)d_in[5];
    const float* Wih_f  = (const float*)d_in[6];
    const float* Whh_f  = (const float*)d_in[7];
    const float* b_f    = (const float*)d_in[8];
    const float* Wih_b  = (const float*)d_in[9];
    const float* Whh_b  = (const float*)d_in[10];
    const float* b_b    = (const float*)d_in[11];
    const float* Wc     = (const float*)d_in[12];
    const float* bc     = (const float*)d_in[13];
    const float* strt   = (const float*)d_in[14];
    const float* endt   = (const float*)d_in[15];
    const float* trans  = (const float*)d_in[16];
    const float* h0     = (const float*)d_in[17];
    const float* c0     = (const float*)d_in[18];

    // ws layout (bytes):
    //   hs_f fp32 6,291,456 @ 0
    //   hs_b fp32 6,291,456 @ 6,291,456
    //   xg_f bf16 12,582,912 @ 12,582,912
    //   xg_b bf16 12,582,912 @ 25,165,824
    //   msg  u64  24,576     @ 37,748,736
    //   done u32  512        @ 37,773,312
    //   abort u32 4          @ 37,773,824
    const size_t need = 37773828;
    if (ws_size < need) {   // clean deterministic failure instead of OOB fault
        k_zero<<<(out_size + 255) / 256, 256, 0, stream>>>((float*)d_out, out_size);
        return;
    }
    char* wsb = (char*)d_ws;
    float* hs_f = (float*)(wsb);
    float* hs_b = (float*)(wsb + 6291456);
    __hip_bfloat16* xg_f = (__hip_bfloat16*)(wsb + 12582912);
    __hip_bfloat16* xg_b = (__hip_bfloat16*)(wsb + 25165824);
    unsigned long long* msg = (unsigned long long*)(wsb + 37748736);
    unsigned* done = (unsigned*)(wsb + 37773312);
    unsigned* abortw = (unsigned*)(wsb + 37773824);

    hipMemsetAsync(msg, 0, 24576 + 512 + 4, stream);  // reset tags+hints+abort

    k_gemm_xg<<<dim3(G4 / 64, SEQ / 64, 2), 256, 0, stream>>>(
        x, casing, pos, we, ce, pe, Wih_f, b_f, Wih_b, b_b, xg_f, xg_b);
    k_lstm<<<2 * NWG, 1024, 0, stream>>>(
        xg_f, xg_b, Whh_f, Whh_b, h0, c0, hs_f, hs_b, msg, done, abortw);
    k_head<<<SEQ / 4, 256, 0, stream>>>(hs_f, hs_b, Wc, bc, (float*)d_out);
    k_viterbi<<<1, 64, 0, stream>>>(
        (const float*)d_out, strt, endt, trans, (float*)d_out + (size_t)SEQ * CDIM);
}